// Round 9
// baseline (180.695 us; speedup 1.0000x reference)
//
#include <hip/hip_runtime.h>
#include <hip/hip_bf16.h>

typedef __hip_bfloat16 bf16;
typedef unsigned short u16;
typedef __attribute__((ext_vector_type(8))) short short8;
typedef __attribute__((ext_vector_type(4))) float floatx4;

#define D_EMBED 1024
#define N_HEADS 16
#define HEAD_DIM 64
#define BATCH 2
#define SEQ 2048
#define ROWS (BATCH * SEQ)          // 4096
#define QKV_COLS (3 * D_EMBED)      // 3072
// exp2-domain scale folded into Q: log2(e)/sqrt(64)
#define QSCALE 0.1803368801f

__device__ __forceinline__ void g2l16(const void* g, void* l) {
    __builtin_amdgcn_global_load_lds(
        (const __attribute__((address_space(1))) unsigned int*)g,
        (__attribute__((address_space(3))) unsigned int*)l,
        16, 0, 0);
}

__device__ __forceinline__ u16 f2b_bits(float f) {
    bf16 h = __float2bfloat16(f);
    u16 u;
    __builtin_memcpy(&u, &h, 2);
    return u;
}

__device__ __forceinline__ unsigned pack2(float a, float b) {   // RNE pack
    return (unsigned)f2b_bits(a) | ((unsigned)f2b_bits(b) << 16);
}

__device__ __forceinline__ float fexp2(float x) {
#if __has_builtin(__builtin_amdgcn_exp2f)
    return __builtin_amdgcn_exp2f(x);
#else
    return exp2f(x);
#endif
}

// pack two fp32 -> two truncated bf16 in one op (low = a, high = b)
__device__ __forceinline__ unsigned permpack(float a, float b) {
#if __has_builtin(__builtin_amdgcn_perm)
    return __builtin_amdgcn_perm(__float_as_uint(b), __float_as_uint(a), 0x07060302u);
#else
    return (__float_as_uint(a) >> 16) | (__float_as_uint(b) & 0xFFFF0000u);
#endif
}

// ---------------------------------------------------------------------------
// Fused prep: cast x -> bf16; transpose+cast w_qkv, w_o.
// ---------------------------------------------------------------------------
__global__ __launch_bounds__(256)
void prep(const float* __restrict__ x, const float* __restrict__ w_qkv,
          const float* __restrict__ w_o, bf16* __restrict__ xb,
          bf16* __restrict__ wqkvT, bf16* __restrict__ woT)
{
    __shared__ u16 T[64][72];
    const int tid = threadIdx.x;
    const int bid = blockIdx.x;

    if (bid < 4096) {
        const int i = bid * 256 + tid;
        const float4 v = reinterpret_cast<const float4*>(x)[i];
        ushort4 o;
        o.x = f2b_bits(v.x); o.y = f2b_bits(v.y);
        o.z = f2b_bits(v.z); o.w = f2b_bits(v.w);
        reinterpret_cast<ushort4*>(xb)[i] = o;
        return;
    }
    const float* in; u16* out; int R, C, bx, by;
    if (bid < 4864) {
        const int t = bid - 4096;
        in = w_qkv; out = reinterpret_cast<u16*>(wqkvT); R = 1024; C = 3072;
        bx = t % 48; by = t / 48;
    } else {
        const int t = bid - 4864;
        in = w_o; out = reinterpret_cast<u16*>(woT); R = 1024; C = 1024;
        bx = t % 16; by = t / 16;
    }
    const int r0 = by * 64, c0 = bx * 64;
#pragma unroll
    for (int it = 0; it < 4; ++it) {
        const int r = (tid >> 4) + it * 16;
        const int c4 = (tid & 15) * 4;
        const float4 v = *reinterpret_cast<const float4*>(in + (size_t)(r0 + r) * C + c0 + c4);
        T[c4 + 0][r] = f2b_bits(v.x);
        T[c4 + 1][r] = f2b_bits(v.y);
        T[c4 + 2][r] = f2b_bits(v.z);
        T[c4 + 3][r] = f2b_bits(v.w);
    }
    __syncthreads();
#pragma unroll
    for (int it = 0; it < 4; ++it) {
        const int rr = (tid >> 4) + it * 16;
        const int cc4 = (tid & 15) * 4;
        ushort4 o = *reinterpret_cast<const ushort4*>(&T[rr][cc4]);
        *reinterpret_cast<ushort4*>(out + (size_t)(c0 + rr) * R + r0 + cc4) = o;
    }
}

// ---------------------------------------------------------------------------
// QKV MFMA GEMM: C[4096,3072] = A @ Bt^T + bias. 128x128 tile, BK=32.
// Epilogue: q (scaled) / k row-major bf16; V stored TRANSPOSED directly into
// vtb[bh*64+d][s] via per-wave LDS column reads.
// ---------------------------------------------------------------------------
__global__ __launch_bounds__(256)
void gemm_qkv(const bf16* __restrict__ A, const bf16* __restrict__ Bt,
              const float* __restrict__ bias,
              bf16* __restrict__ qb, bf16* __restrict__ kb, bf16* __restrict__ vtb)
{
    __shared__ __align__(16) char smem[16384];
    char* As = smem;            // [128 m][32 k] bf16, 64B rows
    char* Bs = smem + 8192;     // [128 n][32 k]

    const int tid = threadIdx.x;
    const int lane = tid & 63, w = tid >> 6;
    const int quad = lane >> 4, l15 = lane & 15;
    const int mw = (w >> 1) * 64, nw = (w & 1) * 64;
    const int blockM = blockIdx.y * 128, blockN = blockIdx.x * 128;

    floatx4 acc[4][4];
#pragma unroll
    for (int i = 0; i < 4; ++i)
#pragma unroll
        for (int j = 0; j < 4; ++j) acc[i][j] = (floatx4){0.f, 0.f, 0.f, 0.f};

    for (int k0 = 0; k0 < 1024; k0 += 32) {
        __syncthreads();
#pragma unroll
        for (int it = 0; it < 2; ++it) {
            const int p = it * 256 + tid;
            const int row = p >> 2, ch = p & 3;
            char* dst = As + (it * 256 + (tid & ~63)) * 16;
            g2l16(A + (size_t)(blockM + row) * 1024 + k0 + ch * 8, dst);
            g2l16(Bt + (size_t)(blockN + row) * 1024 + k0 + ch * 8, dst + 8192);
        }
        __syncthreads();

        short8 af[4], bfr[4];
#pragma unroll
        for (int mi = 0; mi < 4; ++mi)
            af[mi] = *reinterpret_cast<const short8*>(
                As + (mw + mi * 16 + l15) * 64 + quad * 16);
#pragma unroll
        for (int ni = 0; ni < 4; ++ni)
            bfr[ni] = *reinterpret_cast<const short8*>(
                Bs + (nw + ni * 16 + l15) * 64 + quad * 16);
#pragma unroll
        for (int mi = 0; mi < 4; ++mi)
#pragma unroll
            for (int ni = 0; ni < 4; ++ni)
                acc[mi][ni] = __builtin_amdgcn_mfma_f32_16x16x32_bf16(
                    af[mi], bfr[ni], acc[mi][ni], 0, 0, 0);
    }

    // epilogue: per-wave LDS repack
    __syncthreads();
    u16* W = reinterpret_cast<u16*>(smem + w * 2304);   // [16 m][stride 72 u16]
    const bool isq = (blockN < 1024);
    const bool isv = (blockN >= 2048);

    float bvn[4];                        // hoisted bias
#pragma unroll
    for (int ni = 0; ni < 4; ++ni) bvn[ni] = bias[blockN + nw + ni * 16 + l15];

    if (!isv) {
        bf16* dstbuf = isq ? qb : kb;
        const int coloff = blockN - (isq ? 0 : 1024);
#pragma unroll
        for (int mi = 0; mi < 4; ++mi) {
#pragma unroll
            for (int ni = 0; ni < 4; ++ni) {
#pragma unroll
                for (int r = 0; r < 4; ++r) {
                    float val = acc[mi][ni][r] + bvn[ni];
                    if (isq) val *= QSCALE;
                    W[(quad * 4 + r) * 72 + ni * 16 + l15] = f2b_bits(val);
                }
            }
#pragma unroll
            for (int half = 0; half < 2; ++half) {
                const int idx = half * 64 + lane;
                const int rowL = idx >> 3, ch = idx & 7;
                short8 v = *reinterpret_cast<const short8*>(W + rowL * 72 + ch * 8);
                const int grow = blockM + mw + mi * 16 + rowL;
                const int gcol = coloff + nw + ch * 8;
                *reinterpret_cast<short8*>(
                    reinterpret_cast<u16*>(dstbuf) + (size_t)grow * 1024 + gcol) = v;
            }
        }
    } else {
        // V: store transposed to vtb[(b*16+h)*64 + d][s]
        const int col0 = blockN - 2048 + nw;          // multiple of 64
        const int h = col0 >> 6;
        const int bh = (blockM >> 11) * 16 + h;
        const int sb = (blockM & 2047) + mw;
        u16* vdst = reinterpret_cast<u16*>(vtb) + (size_t)bh * 64 * SEQ;
#pragma unroll
        for (int mi = 0; mi < 4; ++mi) {
#pragma unroll
            for (int ni = 0; ni < 4; ++ni) {
#pragma unroll
                for (int r = 0; r < 4; ++r)
                    W[(quad * 4 + r) * 72 + ni * 16 + l15] =
                        f2b_bits(acc[mi][ni][r] + bvn[ni]);
            }
#pragma unroll
            for (int mc = 0; mc < 2; ++mc) {
                u16 tmp[8];
#pragma unroll
                for (int e = 0; e < 8; ++e) tmp[e] = W[(mc * 8 + e) * 72 + lane];
                const int s = sb + mi * 16 + mc * 8;
                *reinterpret_cast<short8*>(vdst + (size_t)lane * SEQ + s) =
                    *reinterpret_cast<const short8*>(tmp);
            }
        }
    }
}

// ---------------------------------------------------------------------------
// Out-proj MFMA GEMM: out[4096,1024] = A @ Bt^T + bias (fp32 out).
// 128m x 64n tile -> 512 blocks (2/CU).
// ---------------------------------------------------------------------------
__global__ __launch_bounds__(256)
void gemm_out(const bf16* __restrict__ A, const bf16* __restrict__ Bt,
              const float* __restrict__ bias, float* __restrict__ outf)
{
    __shared__ __align__(16) char smem[12288];
    char* As = smem;            // [128 m][32 k]
    char* Bs = smem + 8192;     // [64 n][32 k]

    const int tid = threadIdx.x;
    const int lane = tid & 63, w = tid >> 6;
    const int quad = lane >> 4, l15 = lane & 15;
    const int mw = (w >> 1) * 64, nw = (w & 1) * 32;
    const int blockM = blockIdx.y * 128, blockN = blockIdx.x * 64;

    floatx4 acc[4][2];
#pragma unroll
    for (int i = 0; i < 4; ++i)
#pragma unroll
        for (int j = 0; j < 2; ++j) acc[i][j] = (floatx4){0.f, 0.f, 0.f, 0.f};

    for (int k0 = 0; k0 < 1024; k0 += 32) {
        __syncthreads();
#pragma unroll
        for (int it = 0; it < 2; ++it) {
            const int p = it * 256 + tid;
            const int row = p >> 2, ch = p & 3;
            g2l16(A + (size_t)(blockM + row) * 1024 + k0 + ch * 8,
                  As + (it * 256 + (tid & ~63)) * 16);
        }
        {
            const int row = tid >> 2, ch = tid & 3;
            g2l16(Bt + (size_t)(blockN + row) * 1024 + k0 + ch * 8,
                  Bs + (tid & ~63) * 16);
        }
        __syncthreads();

        short8 af[4], bfr[2];
#pragma unroll
        for (int mi = 0; mi < 4; ++mi)
            af[mi] = *reinterpret_cast<const short8*>(
                As + (mw + mi * 16 + l15) * 64 + quad * 16);
#pragma unroll
        for (int ni = 0; ni < 2; ++ni)
            bfr[ni] = *reinterpret_cast<const short8*>(
                Bs + (nw + ni * 16 + l15) * 64 + quad * 16);
#pragma unroll
        for (int mi = 0; mi < 4; ++mi)
#pragma unroll
            for (int ni = 0; ni < 2; ++ni)
                acc[mi][ni] = __builtin_amdgcn_mfma_f32_16x16x32_bf16(
                    af[mi], bfr[ni], acc[mi][ni], 0, 0, 0);
    }

    float bvn[2];
#pragma unroll
    for (int ni = 0; ni < 2; ++ni) bvn[ni] = bias[blockN + nw + ni * 16 + l15];

#pragma unroll
    for (int mi = 0; mi < 4; ++mi)
#pragma unroll
        for (int r = 0; r < 4; ++r) {
            const int row = blockM + mw + mi * 16 + quad * 4 + r;
#pragma unroll
            for (int ni = 0; ni < 2; ++ni) {
                const int col = blockN + nw + ni * 16 + l15;
                outf[(size_t)row * 1024 + col] = acc[mi][ni][r] + bvn[ni];
            }
        }
}

// ---------------------------------------------------------------------------
// MFMA flash attention (causal), max-free exp2-domain softmax.
// Merged union k-loop (block (i,bh) owns q-tiles i and 31-i), K/V dbuf.
// Round 9: k-loop UNROLLED x2 with compile-time KV0/KV1 bases (all LDS
// addresses immediate-offset), Q staged into KV1 (register fragments after
// one read) -> LDS 40 KB. Hoisted staging pointers.
// ---------------------------------------------------------------------------
__global__ __launch_bounds__(256)
void attn_mfma(const bf16* __restrict__ qb, const bf16* __restrict__ kb,
               const bf16* __restrict__ vtb, bf16* __restrict__ ob)
{
    __shared__ __align__(16) char smem[40960];
    char* KV0 = smem;                     // K 8K + V 8K
    char* KV1 = smem + 16384;             // K 8K + V 8K (initially Q staging)
    const int tid = threadIdx.x;
    const int lane = tid & 63, w = tid >> 6;
    const int quad = lane >> 4, l15 = lane & 15;
    char* Ps = smem + 32768 + w * 2048;   // per-wave [8 kchunk][16 q][16B]

    const int pi = blockIdx.x;            // 0..15
    const int bh = blockIdx.y;
    const int b = bh >> 4, h = bh & 15;

    const int qtS = pi, qtB = 31 - pi;
    const int q0S = qtS * 64, q0B = qtB * 64;
    const int KT = qtB + 1;               // 17..32
    const int qrowS = q0S + w * 16 + l15;
    const int qrowB = q0B + w * 16 + l15;

    const size_t kvrow = (size_t)b * SEQ;
    const size_t vbase = (size_t)bh * 64 * SEQ;

    const short8 ones = {0x3F80, 0x3F80, 0x3F80, 0x3F80,
                         0x3F80, 0x3F80, 0x3F80, 0x3F80};   // bf16 1.0 x8

    // hoisted staging geometry: row1 = row0+32, lch identical (32 % 8 == 0)
    const int row0 = tid >> 3;
    const int lch = (tid & 7) ^ (row0 & 7);
    const int loff0 = (tid & ~63) * 16;
    const int loff1 = loff0 + 4096;
    const bf16* ksrc0 = kb + (kvrow + row0) * D_EMBED + h * 64 + lch * 8;
    const bf16* ksrc1 = ksrc0 + (size_t)32 * D_EMBED;
    const bf16* vsrc0 = vtb + vbase + (size_t)row0 * SEQ + lch * 8;
    const bf16* vsrc1 = vsrc0 + (size_t)32 * SEQ;

    // stage Q tiles into KV1 (dead after fragment load) + K/V kt=0 into KV0
    {
        const bf16* qsrcS = qb + (kvrow + q0S + row0) * D_EMBED + h * 64 + lch * 8;
        const bf16* qsrcB = qb + (kvrow + q0B + row0) * D_EMBED + h * 64 + lch * 8;
        g2l16(qsrcS, KV1 + loff0);
        g2l16(qsrcS + (size_t)32 * D_EMBED, KV1 + loff1);
        g2l16(qsrcB, KV1 + 8192 + loff0);
        g2l16(qsrcB + (size_t)32 * D_EMBED, KV1 + 8192 + loff1);
        g2l16(ksrc0, KV0 + loff0);
        g2l16(ksrc1, KV0 + loff1);
        g2l16(vsrc0, KV0 + 8192 + loff0);
        g2l16(vsrc1, KV0 + 8192 + loff1);
    }
    __syncthreads();

    const int qoff = (w * 16 + l15) * 128;
    const int x0 = (quad ^ (l15 & 7)) * 16;
    const int x1 = ((quad + 4) ^ (l15 & 7)) * 16;
    const short8 qS0 = *reinterpret_cast<const short8*>(KV1 + qoff + x0);
    const short8 qS1 = *reinterpret_cast<const short8*>(KV1 + qoff + x1);
    const short8 qB0 = *reinterpret_cast<const short8*>(KV1 + 8192 + qoff + x0);
    const short8 qB1 = *reinterpret_cast<const short8*>(KV1 + 8192 + qoff + x1);
    __syncthreads();    // Q reads done; KV1 free for prefetch

    floatx4 OaccS[4], OaccB[4], LaccS, LaccB;
#pragma unroll
    for (int i = 0; i < 4; ++i) {
        OaccS[i] = (floatx4){0.f, 0.f, 0.f, 0.f};
        OaccB[i] = (floatx4){0.f, 0.f, 0.f, 0.f};
    }
    LaccS = (floatx4){0.f, 0.f, 0.f, 0.f};
    LaccB = (floatx4){0.f, 0.f, 0.f, 0.f};

    auto prefetch = [&](int nkt, char* dst) {
        const size_t ko = (size_t)nkt * 64;
        g2l16(ksrc0 + ko * D_EMBED, dst + loff0);
        g2l16(ksrc1 + ko * D_EMBED, dst + loff1);
        g2l16(vsrc0 + ko, dst + 8192 + loff0);
        g2l16(vsrc1 + ko, dst + 8192 + loff1);
    };

    auto compute = [&](int kt, char* Ks, char* Vs) {
        const int k0 = kt * 64;
        // K/V fragments, shared across both q-computes
        short8 kf[2][4], vf[2][4];
#pragma unroll
        for (int ms = 0; ms < 4; ++ms) {
            const int roff = (ms * 16 + l15) * 128;
            kf[0][ms] = *reinterpret_cast<const short8*>(Ks + roff + x0);
            kf[1][ms] = *reinterpret_cast<const short8*>(Ks + roff + x1);
        }
#pragma unroll
        for (int ks = 0; ks < 2; ++ks)
#pragma unroll
            for (int ds = 0; ds < 4; ++ds)
                vf[ks][ds] = *reinterpret_cast<const short8*>(
                    Vs + (ds * 16 + l15) * 128 + (((quad + ks * 4) ^ (l15 & 7)) * 16));

        // ---- big q-tile (always) ----
        {
            floatx4 S[4];
#pragma unroll
            for (int ms = 0; ms < 4; ++ms) {
                floatx4 t = (floatx4){0.f, 0.f, 0.f, 0.f};
                t = __builtin_amdgcn_mfma_f32_16x16x32_bf16(kf[0][ms], qB0, t, 0, 0, 0);
                S[ms] = __builtin_amdgcn_mfma_f32_16x16x32_bf16(kf[1][ms], qB1, t, 0, 0, 0);
            }
            const bool diag = (kt == KT - 1);
#pragma unroll
            for (int ms = 0; ms < 4; ++ms) {
                float p[4];
#pragma unroll
                for (int r = 0; r < 4; ++r) {
                    float s = S[ms][r];
                    if (diag && (k0 + ms * 16 + quad * 4 + r) > qrowB) s = -1e30f;
                    p[r] = fexp2(s);
                }
                const int k = ms * 16 + quad * 4;
                uint2 pw;
                pw.x = permpack(p[0], p[1]);
                pw.y = permpack(p[2], p[3]);
                *reinterpret_cast<uint2*>(Ps + (k >> 3) * 256 + l15 * 16 + (k & 7) * 2) = pw;
            }
#pragma unroll
            for (int ks = 0; ks < 2; ++ks) {
                const short8 pf = *reinterpret_cast<const short8*>(
                    Ps + (ks * 4 + quad) * 256 + l15 * 16);
                LaccB = __builtin_amdgcn_mfma_f32_16x16x32_bf16(ones, pf, LaccB, 0, 0, 0);
#pragma unroll
                for (int ds = 0; ds < 4; ++ds)
                    OaccB[ds] = __builtin_amdgcn_mfma_f32_16x16x32_bf16(
                        vf[ks][ds], pf, OaccB[ds], 0, 0, 0);
            }
        }

        // ---- small q-tile (while kt <= qtS) ----
        if (kt <= qtS) {
            floatx4 S[4];
#pragma unroll
            for (int ms = 0; ms < 4; ++ms) {
                floatx4 t = (floatx4){0.f, 0.f, 0.f, 0.f};
                t = __builtin_amdgcn_mfma_f32_16x16x32_bf16(kf[0][ms], qS0, t, 0, 0, 0);
                S[ms] = __builtin_amdgcn_mfma_f32_16x16x32_bf16(kf[1][ms], qS1, t, 0, 0, 0);
            }
            const bool diag = (kt == qtS);
#pragma unroll
            for (int ms = 0; ms < 4; ++ms) {
                float p[4];
#pragma unroll
                for (int r = 0; r < 4; ++r) {
                    float s = S[ms][r];
                    if (diag && (k0 + ms * 16 + quad * 4 + r) > qrowS) s = -1e30f;
                    p[r] = fexp2(s);
                }
                const int k = ms * 16 + quad * 4;
                uint2 pw;
                pw.x = permpack(p[0], p[1]);
                pw.y = permpack(p[2], p[3]);
                *reinterpret_cast<uint2*>(Ps + (k >> 3) * 256 + l15 * 16 + (k & 7) * 2) = pw;
            }
#pragma unroll
            for (int ks = 0; ks < 2; ++ks) {
                const short8 pf = *reinterpret_cast<const short8*>(
                    Ps + (ks * 4 + quad) * 256 + l15 * 16);
                LaccS = __builtin_amdgcn_mfma_f32_16x16x32_bf16(ones, pf, LaccS, 0, 0, 0);
#pragma unroll
                for (int ds = 0; ds < 4; ++ds)
                    OaccS[ds] = __builtin_amdgcn_mfma_f32_16x16x32_bf16(
                        vf[ks][ds], pf, OaccS[ds], 0, 0, 0);
            }
        }
    };

    // k-loop, unrolled x2 with compile-time buffer bases
#pragma unroll 1
    for (int kt = 0; kt < KT; kt += 2) {
        // step A: compute KV0, prefetch kt+1 -> KV1
        if (kt + 1 < KT) prefetch(kt + 1, KV1);
        compute(kt, KV0, KV0 + 8192);
        __syncthreads();
        if (kt + 1 >= KT) break;
        // step B: compute KV1, prefetch kt+2 -> KV0
        if (kt + 2 < KT) prefetch(kt + 2, KV0);
        compute(kt + 1, KV1, KV1 + 8192);
        __syncthreads();
    }

    // epilogue: O^T/l -> per-wave LDS [q][d] -> coalesced 16B stores (both tiles)
#pragma unroll
    for (int which = 0; which < 2; ++which) {
        const floatx4* Oacc = which ? OaccB : OaccS;
        const float invl = 1.f / (which ? LaccB[0] : LaccS[0]);
        const int q0 = which ? q0B : q0S;
#pragma unroll
        for (int ds = 0; ds < 4; ++ds) {
            const int d = ds * 16 + quad * 4;
            uint2 ow;
            ow.x = pack2(Oacc[ds][0] * invl, Oacc[ds][1] * invl);
            ow.y = pack2(Oacc[ds][2] * invl, Oacc[ds][3] * invl);
            *reinterpret_cast<uint2*>(
                Ps + (d >> 3) * 256 + l15 * 16 + (d & 7) * 2) = ow;
        }
#pragma unroll
        for (int it = 0; it < 2; ++it) {
            const int idx = it * 64 + lane;
            const int ch = idx >> 4, q = idx & 15;
            short8 ov = *reinterpret_cast<const short8*>(Ps + ch * 256 + q * 16);
            *reinterpret_cast<short8*>(
                ob + (kvrow + q0 + w * 16 + q) * D_EMBED + h * 64 + ch * 8) = ov;
        }
    }
}

// ---------------------------------------------------------------------------
extern "C" void kernel_launch(void* const* d_in, const int* in_sizes, int n_in,
                              void* d_out, int out_size, void* d_ws, size_t ws_size,
                              hipStream_t stream)
{
    const float* x     = (const float*)d_in[0];   // [4096, 1024]
    const float* w_qkv = (const float*)d_in[1];   // [1024, 3072]
    const float* b_qkv = (const float*)d_in[2];   // [3072]
    const float* w_o   = (const float*)d_in[3];   // [1024, 1024]
    const float* b_o   = (const float*)d_in[4];   // [1024]
    float* out = (float*)d_out;                   // [4096, 1024] fp32

    bf16* xb     = (bf16*)d_ws;                    // [4096][1024]
    bf16* wqkvT  = xb + (size_t)4096 * 1024;       // [3072][1024]
    bf16* woT    = wqkvT + (size_t)3072 * 1024;    // [1024][1024]
    bf16* qbuf   = woT + (size_t)1024 * 1024;      // [4096][1024] (pre-scaled)
    bf16* kbuf   = qbuf + (size_t)4096 * 1024;     // [4096][1024]
    bf16* vtb    = kbuf + (size_t)4096 * 1024;     // [32 bh][64 d][2048 s]
    bf16* attnb  = vtb + (size_t)4096 * 1024;      // [4096][1024]

    dim3 blk(256);

    // fused casts
    prep<<<dim3(5120), blk, 0, stream>>>(x, w_qkv, w_o, xb, wqkvT, woT);

    // QKV projection (q scaled, k row-major, V transposed directly)
    gemm_qkv<<<dim3(24, 32), blk, 0, stream>>>(xb, wqkvT, b_qkv, qbuf, kbuf, vtb);

    // flash attention: merged-pair causal blocks, K/V dbuf, unrolled x2
    attn_mfma<<<dim3(16, 32), blk, 0, stream>>>(qbuf, kbuf, vtb, attnb);

    // output projection (fp32 out + bias), 512 blocks
    gemm_out<<<dim3(16, 32), blk, 0, stream>>>(attnb, woT, b_o, out);
}

// Round 10
// 178.858 us; speedup vs baseline: 1.0103x; 1.0103x over previous
//
#include <hip/hip_runtime.h>
#include <hip/hip_bf16.h>

typedef __hip_bfloat16 bf16;
typedef unsigned short u16;
typedef __attribute__((ext_vector_type(8))) short short8;
typedef __attribute__((ext_vector_type(4))) float floatx4;

#define D_EMBED 1024
#define N_HEADS 16
#define HEAD_DIM 64
#define BATCH 2
#define SEQ 2048
#define ROWS (BATCH * SEQ)          // 4096
#define QKV_COLS (3 * D_EMBED)      // 3072
// exp2-domain scale folded into Q: log2(e)/sqrt(64)
#define QSCALE 0.1803368801f

__device__ __forceinline__ void g2l16(const void* g, void* l) {
    __builtin_amdgcn_global_load_lds(
        (const __attribute__((address_space(1))) unsigned int*)g,
        (__attribute__((address_space(3))) unsigned int*)l,
        16, 0, 0);
}

__device__ __forceinline__ u16 f2b_bits(float f) {
    bf16 h = __float2bfloat16(f);
    u16 u;
    __builtin_memcpy(&u, &h, 2);
    return u;
}

__device__ __forceinline__ unsigned pack2(float a, float b) {   // RNE pack
    return (unsigned)f2b_bits(a) | ((unsigned)f2b_bits(b) << 16);
}

__device__ __forceinline__ float fexp2(float x) {
#if __has_builtin(__builtin_amdgcn_exp2f)
    return __builtin_amdgcn_exp2f(x);
#else
    return exp2f(x);
#endif
}

// pack two fp32 -> two truncated bf16 in one op (low = a, high = b)
__device__ __forceinline__ unsigned permpack(float a, float b) {
#if __has_builtin(__builtin_amdgcn_perm)
    return __builtin_amdgcn_perm(__float_as_uint(b), __float_as_uint(a), 0x07060302u);
#else
    return (__float_as_uint(a) >> 16) | (__float_as_uint(b) & 0xFFFF0000u);
#endif
}

// ---------------------------------------------------------------------------
// Fused prep: cast x -> bf16; transpose+cast w_qkv, w_o.
// ---------------------------------------------------------------------------
__global__ __launch_bounds__(256)
void prep(const float* __restrict__ x, const float* __restrict__ w_qkv,
          const float* __restrict__ w_o, bf16* __restrict__ xb,
          bf16* __restrict__ wqkvT, bf16* __restrict__ woT)
{
    __shared__ u16 T[64][72];
    const int tid = threadIdx.x;
    const int bid = blockIdx.x;

    if (bid < 4096) {
        const int i = bid * 256 + tid;
        const float4 v = reinterpret_cast<const float4*>(x)[i];
        ushort4 o;
        o.x = f2b_bits(v.x); o.y = f2b_bits(v.y);
        o.z = f2b_bits(v.z); o.w = f2b_bits(v.w);
        reinterpret_cast<ushort4*>(xb)[i] = o;
        return;
    }
    const float* in; u16* out; int R, C, bx, by;
    if (bid < 4864) {
        const int t = bid - 4096;
        in = w_qkv; out = reinterpret_cast<u16*>(wqkvT); R = 1024; C = 3072;
        bx = t % 48; by = t / 48;
    } else {
        const int t = bid - 4864;
        in = w_o; out = reinterpret_cast<u16*>(woT); R = 1024; C = 1024;
        bx = t % 16; by = t / 16;
    }
    const int r0 = by * 64, c0 = bx * 64;
#pragma unroll
    for (int it = 0; it < 4; ++it) {
        const int r = (tid >> 4) + it * 16;
        const int c4 = (tid & 15) * 4;
        const float4 v = *reinterpret_cast<const float4*>(in + (size_t)(r0 + r) * C + c0 + c4);
        T[c4 + 0][r] = f2b_bits(v.x);
        T[c4 + 1][r] = f2b_bits(v.y);
        T[c4 + 2][r] = f2b_bits(v.z);
        T[c4 + 3][r] = f2b_bits(v.w);
    }
    __syncthreads();
#pragma unroll
    for (int it = 0; it < 4; ++it) {
        const int rr = (tid >> 4) + it * 16;
        const int cc4 = (tid & 15) * 4;
        ushort4 o = *reinterpret_cast<const ushort4*>(&T[rr][cc4]);
        *reinterpret_cast<ushort4*>(out + (size_t)(c0 + rr) * R + r0 + cc4) = o;
    }
}

// ---------------------------------------------------------------------------
// QKV MFMA GEMM: C[4096,3072] = A @ Bt^T + bias. 128x128 tile, BK=32,
// DOUBLE-BUFFERED staging (prefetch k+32 during compute, 1 barrier/iter).
// Epilogue: q (scaled) / k row-major bf16; V stored TRANSPOSED into
// vtb[bh*64+d][s] via per-wave LDS column reads.
// ---------------------------------------------------------------------------
__global__ __launch_bounds__(256)
void gemm_qkv(const bf16* __restrict__ A, const bf16* __restrict__ Bt,
              const float* __restrict__ bias,
              bf16* __restrict__ qb, bf16* __restrict__ kb, bf16* __restrict__ vtb)
{
    __shared__ __align__(16) char smem[32768];
    char* BUF0 = smem;            // As 8K + Bs 8K
    char* BUF1 = smem + 16384;

    const int tid = threadIdx.x;
    const int lane = tid & 63, w = tid >> 6;
    const int quad = lane >> 4, l15 = lane & 15;
    const int mw = (w >> 1) * 64, nw = (w & 1) * 64;
    const int blockM = blockIdx.y * 128, blockN = blockIdx.x * 128;

    // hoisted staging geometry: rows (tid>>2) and +64, k-chunk (tid&3)*8
    const int row0 = tid >> 2, ch = tid & 3;
    const int off0 = (tid & ~63) * 16;
    const bf16* Asrc0 = A + (size_t)(blockM + row0) * 1024 + ch * 8;
    const bf16* Asrc1 = Asrc0 + (size_t)64 * 1024;
    const bf16* Bsrc0 = Bt + (size_t)(blockN + row0) * 1024 + ch * 8;
    const bf16* Bsrc1 = Bsrc0 + (size_t)64 * 1024;

    auto stage = [&](int k0, char* buf) {
        g2l16(Asrc0 + k0, buf + off0);
        g2l16(Asrc1 + k0, buf + off0 + 4096);
        g2l16(Bsrc0 + k0, buf + 8192 + off0);
        g2l16(Bsrc1 + k0, buf + 8192 + off0 + 4096);
    };

    floatx4 acc[4][4];
#pragma unroll
    for (int i = 0; i < 4; ++i)
#pragma unroll
        for (int j = 0; j < 4; ++j) acc[i][j] = (floatx4){0.f, 0.f, 0.f, 0.f};

    auto compute = [&](char* buf) {
        short8 af[4], bfr[4];
#pragma unroll
        for (int mi = 0; mi < 4; ++mi)
            af[mi] = *reinterpret_cast<const short8*>(
                buf + (mw + mi * 16 + l15) * 64 + quad * 16);
#pragma unroll
        for (int ni = 0; ni < 4; ++ni)
            bfr[ni] = *reinterpret_cast<const short8*>(
                buf + 8192 + (nw + ni * 16 + l15) * 64 + quad * 16);
#pragma unroll
        for (int mi = 0; mi < 4; ++mi)
#pragma unroll
            for (int ni = 0; ni < 4; ++ni)
                acc[mi][ni] = __builtin_amdgcn_mfma_f32_16x16x32_bf16(
                    af[mi], bfr[ni], acc[mi][ni], 0, 0, 0);
    };

    stage(0, BUF0);
    __syncthreads();
#pragma unroll 1
    for (int k0 = 0; k0 < 1024; k0 += 64) {
        if (k0 + 32 < 1024) stage(k0 + 32, BUF1);
        compute(BUF0);
        __syncthreads();
        if (k0 + 64 < 1024) stage(k0 + 64, BUF0);
        compute(BUF1);
        __syncthreads();
    }

    // epilogue: per-wave LDS repack
    u16* W = reinterpret_cast<u16*>(smem + w * 2304);   // [16 m][stride 72 u16]
    const bool isq = (blockN < 1024);
    const bool isv = (blockN >= 2048);

    float bvn[4];                        // hoisted bias
#pragma unroll
    for (int ni = 0; ni < 4; ++ni) bvn[ni] = bias[blockN + nw + ni * 16 + l15];

    if (!isv) {
        bf16* dstbuf = isq ? qb : kb;
        const int coloff = blockN - (isq ? 0 : 1024);
#pragma unroll
        for (int mi = 0; mi < 4; ++mi) {
#pragma unroll
            for (int ni = 0; ni < 4; ++ni) {
#pragma unroll
                for (int r = 0; r < 4; ++r) {
                    float val = acc[mi][ni][r] + bvn[ni];
                    if (isq) val *= QSCALE;
                    W[(quad * 4 + r) * 72 + ni * 16 + l15] = f2b_bits(val);
                }
            }
#pragma unroll
            for (int half = 0; half < 2; ++half) {
                const int idx = half * 64 + lane;
                const int rowL = idx >> 3, chh = idx & 7;
                short8 v = *reinterpret_cast<const short8*>(W + rowL * 72 + chh * 8);
                const int grow = blockM + mw + mi * 16 + rowL;
                const int gcol = coloff + nw + chh * 8;
                *reinterpret_cast<short8*>(
                    reinterpret_cast<u16*>(dstbuf) + (size_t)grow * 1024 + gcol) = v;
            }
        }
    } else {
        // V: store transposed to vtb[(b*16+h)*64 + d][s]
        const int col0 = blockN - 2048 + nw;          // multiple of 64
        const int h = col0 >> 6;
        const int bh = (blockM >> 11) * 16 + h;
        const int sb = (blockM & 2047) + mw;
        u16* vdst = reinterpret_cast<u16*>(vtb) + (size_t)bh * 64 * SEQ;
#pragma unroll
        for (int mi = 0; mi < 4; ++mi) {
#pragma unroll
            for (int ni = 0; ni < 4; ++ni) {
#pragma unroll
                for (int r = 0; r < 4; ++r)
                    W[(quad * 4 + r) * 72 + ni * 16 + l15] =
                        f2b_bits(acc[mi][ni][r] + bvn[ni]);
            }
#pragma unroll
            for (int mc = 0; mc < 2; ++mc) {
                u16 tmp[8];
#pragma unroll
                for (int e = 0; e < 8; ++e) tmp[e] = W[(mc * 8 + e) * 72 + lane];
                const int s = sb + mi * 16 + mc * 8;
                *reinterpret_cast<short8*>(vdst + (size_t)lane * SEQ + s) =
                    *reinterpret_cast<const short8*>(tmp);
            }
        }
    }
}

// ---------------------------------------------------------------------------
// Out-proj MFMA GEMM: out[4096,1024] = A @ Bt^T + bias (fp32 out).
// 128m x 64n tile -> 512 blocks (2/CU). DOUBLE-BUFFERED staging.
// ---------------------------------------------------------------------------
__global__ __launch_bounds__(256)
void gemm_out(const bf16* __restrict__ A, const bf16* __restrict__ Bt,
              const float* __restrict__ bias, float* __restrict__ outf)
{
    __shared__ __align__(16) char smem[24576];
    char* BUF0 = smem;            // As 8K + Bs 4K
    char* BUF1 = smem + 12288;

    const int tid = threadIdx.x;
    const int lane = tid & 63, w = tid >> 6;
    const int quad = lane >> 4, l15 = lane & 15;
    const int mw = (w >> 1) * 64, nw = (w & 1) * 32;
    const int blockM = blockIdx.y * 128, blockN = blockIdx.x * 64;

    const int row0 = tid >> 2, ch = tid & 3;
    const int off0 = (tid & ~63) * 16;
    const bf16* Asrc0 = A + (size_t)(blockM + row0) * 1024 + ch * 8;
    const bf16* Asrc1 = Asrc0 + (size_t)64 * 1024;
    const bf16* Bsrc0 = Bt + (size_t)(blockN + row0) * 1024 + ch * 8;

    auto stage = [&](int k0, char* buf) {
        g2l16(Asrc0 + k0, buf + off0);
        g2l16(Asrc1 + k0, buf + off0 + 4096);
        g2l16(Bsrc0 + k0, buf + 8192 + off0);
    };

    floatx4 acc[4][2];
#pragma unroll
    for (int i = 0; i < 4; ++i)
#pragma unroll
        for (int j = 0; j < 2; ++j) acc[i][j] = (floatx4){0.f, 0.f, 0.f, 0.f};

    auto compute = [&](char* buf) {
        short8 af[4], bfr[2];
#pragma unroll
        for (int mi = 0; mi < 4; ++mi)
            af[mi] = *reinterpret_cast<const short8*>(
                buf + (mw + mi * 16 + l15) * 64 + quad * 16);
#pragma unroll
        for (int ni = 0; ni < 2; ++ni)
            bfr[ni] = *reinterpret_cast<const short8*>(
                buf + 8192 + (nw + ni * 16 + l15) * 64 + quad * 16);
#pragma unroll
        for (int mi = 0; mi < 4; ++mi)
#pragma unroll
            for (int ni = 0; ni < 2; ++ni)
                acc[mi][ni] = __builtin_amdgcn_mfma_f32_16x16x32_bf16(
                    af[mi], bfr[ni], acc[mi][ni], 0, 0, 0);
    };

    stage(0, BUF0);
    __syncthreads();
#pragma unroll 1
    for (int k0 = 0; k0 < 1024; k0 += 64) {
        if (k0 + 32 < 1024) stage(k0 + 32, BUF1);
        compute(BUF0);
        __syncthreads();
        if (k0 + 64 < 1024) stage(k0 + 64, BUF0);
        compute(BUF1);
        __syncthreads();
    }

    float bvn[2];
#pragma unroll
    for (int ni = 0; ni < 2; ++ni) bvn[ni] = bias[blockN + nw + ni * 16 + l15];

#pragma unroll
    for (int mi = 0; mi < 4; ++mi)
#pragma unroll
        for (int r = 0; r < 4; ++r) {
            const int row = blockM + mw + mi * 16 + quad * 4 + r;
#pragma unroll
            for (int ni = 0; ni < 2; ++ni) {
                const int col = blockN + nw + ni * 16 + l15;
                outf[(size_t)row * 1024 + col] = acc[mi][ni][r] + bvn[ni];
            }
        }
}

// ---------------------------------------------------------------------------
// MFMA flash attention (causal), max-free exp2-domain softmax.
// Merged union k-loop (block (i,bh) owns q-tiles i and 31-i), K/V dbuf,
// unrolled x2 with compile-time buffer bases; Q staged into KV1 then
// register-resident. LDS 40 KB.
// ---------------------------------------------------------------------------
__global__ __launch_bounds__(256)
void attn_mfma(const bf16* __restrict__ qb, const bf16* __restrict__ kb,
               const bf16* __restrict__ vtb, bf16* __restrict__ ob)
{
    __shared__ __align__(16) char smem[40960];
    char* KV0 = smem;                     // K 8K + V 8K
    char* KV1 = smem + 16384;             // K 8K + V 8K (initially Q staging)
    const int tid = threadIdx.x;
    const int lane = tid & 63, w = tid >> 6;
    const int quad = lane >> 4, l15 = lane & 15;
    char* Ps = smem + 32768 + w * 2048;   // per-wave [8 kchunk][16 q][16B]

    const int pi = blockIdx.x;            // 0..15
    const int bh = blockIdx.y;
    const int b = bh >> 4, h = bh & 15;

    const int qtS = pi, qtB = 31 - pi;
    const int q0S = qtS * 64, q0B = qtB * 64;
    const int KT = qtB + 1;               // 17..32
    const int qrowS = q0S + w * 16 + l15;
    const int qrowB = q0B + w * 16 + l15;

    const size_t kvrow = (size_t)b * SEQ;
    const size_t vbase = (size_t)bh * 64 * SEQ;

    const short8 ones = {0x3F80, 0x3F80, 0x3F80, 0x3F80,
                         0x3F80, 0x3F80, 0x3F80, 0x3F80};   // bf16 1.0 x8

    // hoisted staging geometry: row1 = row0+32, lch identical (32 % 8 == 0)
    const int row0 = tid >> 3;
    const int lch = (tid & 7) ^ (row0 & 7);
    const int loff0 = (tid & ~63) * 16;
    const int loff1 = loff0 + 4096;
    const bf16* ksrc0 = kb + (kvrow + row0) * D_EMBED + h * 64 + lch * 8;
    const bf16* ksrc1 = ksrc0 + (size_t)32 * D_EMBED;
    const bf16* vsrc0 = vtb + vbase + (size_t)row0 * SEQ + lch * 8;
    const bf16* vsrc1 = vsrc0 + (size_t)32 * SEQ;

    // stage Q tiles into KV1 (dead after fragment load) + K/V kt=0 into KV0
    {
        const bf16* qsrcS = qb + (kvrow + q0S + row0) * D_EMBED + h * 64 + lch * 8;
        const bf16* qsrcB = qb + (kvrow + q0B + row0) * D_EMBED + h * 64 + lch * 8;
        g2l16(qsrcS, KV1 + loff0);
        g2l16(qsrcS + (size_t)32 * D_EMBED, KV1 + loff1);
        g2l16(qsrcB, KV1 + 8192 + loff0);
        g2l16(qsrcB + (size_t)32 * D_EMBED, KV1 + 8192 + loff1);
        g2l16(ksrc0, KV0 + loff0);
        g2l16(ksrc1, KV0 + loff1);
        g2l16(vsrc0, KV0 + 8192 + loff0);
        g2l16(vsrc1, KV0 + 8192 + loff1);
    }
    __syncthreads();

    const int qoff = (w * 16 + l15) * 128;
    const int x0 = (quad ^ (l15 & 7)) * 16;
    const int x1 = ((quad + 4) ^ (l15 & 7)) * 16;
    const short8 qS0 = *reinterpret_cast<const short8*>(KV1 + qoff + x0);
    const short8 qS1 = *reinterpret_cast<const short8*>(KV1 + qoff + x1);
    const short8 qB0 = *reinterpret_cast<const short8*>(KV1 + 8192 + qoff + x0);
    const short8 qB1 = *reinterpret_cast<const short8*>(KV1 + 8192 + qoff + x1);
    __syncthreads();    // Q reads done; KV1 free for prefetch

    floatx4 OaccS[4], OaccB[4], LaccS, LaccB;
#pragma unroll
    for (int i = 0; i < 4; ++i) {
        OaccS[i] = (floatx4){0.f, 0.f, 0.f, 0.f};
        OaccB[i] = (floatx4){0.f, 0.f, 0.f, 0.f};
    }
    LaccS = (floatx4){0.f, 0.f, 0.f, 0.f};
    LaccB = (floatx4){0.f, 0.f, 0.f, 0.f};

    auto prefetch = [&](int nkt, char* dst) {
        const size_t ko = (size_t)nkt * 64;
        g2l16(ksrc0 + ko * D_EMBED, dst + loff0);
        g2l16(ksrc1 + ko * D_EMBED, dst + loff1);
        g2l16(vsrc0 + ko, dst + 8192 + loff0);
        g2l16(vsrc1 + ko, dst + 8192 + loff1);
    };

    auto compute = [&](int kt, char* Ks, char* Vs) {
        const int k0 = kt * 64;
        short8 kf[2][4], vf[2][4];
#pragma unroll
        for (int ms = 0; ms < 4; ++ms) {
            const int roff = (ms * 16 + l15) * 128;
            kf[0][ms] = *reinterpret_cast<const short8*>(Ks + roff + x0);
            kf[1][ms] = *reinterpret_cast<const short8*>(Ks + roff + x1);
        }
#pragma unroll
        for (int ks = 0; ks < 2; ++ks)
#pragma unroll
            for (int ds = 0; ds < 4; ++ds)
                vf[ks][ds] = *reinterpret_cast<const short8*>(
                    Vs + (ds * 16 + l15) * 128 + (((quad + ks * 4) ^ (l15 & 7)) * 16));

        // ---- big q-tile (always) ----
        {
            floatx4 S[4];
#pragma unroll
            for (int ms = 0; ms < 4; ++ms) {
                floatx4 t = (floatx4){0.f, 0.f, 0.f, 0.f};
                t = __builtin_amdgcn_mfma_f32_16x16x32_bf16(kf[0][ms], qB0, t, 0, 0, 0);
                S[ms] = __builtin_amdgcn_mfma_f32_16x16x32_bf16(kf[1][ms], qB1, t, 0, 0, 0);
            }
            const bool diag = (kt == KT - 1);
#pragma unroll
            for (int ms = 0; ms < 4; ++ms) {
                float p[4];
#pragma unroll
                for (int r = 0; r < 4; ++r) {
                    float s = S[ms][r];
                    if (diag && (k0 + ms * 16 + quad * 4 + r) > qrowB) s = -1e30f;
                    p[r] = fexp2(s);
                }
                const int k = ms * 16 + quad * 4;
                uint2 pw;
                pw.x = permpack(p[0], p[1]);
                pw.y = permpack(p[2], p[3]);
                *reinterpret_cast<uint2*>(Ps + (k >> 3) * 256 + l15 * 16 + (k & 7) * 2) = pw;
            }
#pragma unroll
            for (int ks = 0; ks < 2; ++ks) {
                const short8 pf = *reinterpret_cast<const short8*>(
                    Ps + (ks * 4 + quad) * 256 + l15 * 16);
                LaccB = __builtin_amdgcn_mfma_f32_16x16x32_bf16(ones, pf, LaccB, 0, 0, 0);
#pragma unroll
                for (int ds = 0; ds < 4; ++ds)
                    OaccB[ds] = __builtin_amdgcn_mfma_f32_16x16x32_bf16(
                        vf[ks][ds], pf, OaccB[ds], 0, 0, 0);
            }
        }

        // ---- small q-tile (while kt <= qtS) ----
        if (kt <= qtS) {
            floatx4 S[4];
#pragma unroll
            for (int ms = 0; ms < 4; ++ms) {
                floatx4 t = (floatx4){0.f, 0.f, 0.f, 0.f};
                t = __builtin_amdgcn_mfma_f32_16x16x32_bf16(kf[0][ms], qS0, t, 0, 0, 0);
                S[ms] = __builtin_amdgcn_mfma_f32_16x16x32_bf16(kf[1][ms], qS1, t, 0, 0, 0);
            }
            const bool diag = (kt == qtS);
#pragma unroll
            for (int ms = 0; ms < 4; ++ms) {
                float p[4];
#pragma unroll
                for (int r = 0; r < 4; ++r) {
                    float s = S[ms][r];
                    if (diag && (k0 + ms * 16 + quad * 4 + r) > qrowS) s = -1e30f;
                    p[r] = fexp2(s);
                }
                const int k = ms * 16 + quad * 4;
                uint2 pw;
                pw.x = permpack(p[0], p[1]);
                pw.y = permpack(p[2], p[3]);
                *reinterpret_cast<uint2*>(Ps + (k >> 3) * 256 + l15 * 16 + (k & 7) * 2) = pw;
            }
#pragma unroll
            for (int ks = 0; ks < 2; ++ks) {
                const short8 pf = *reinterpret_cast<const short8*>(
                    Ps + (ks * 4 + quad) * 256 + l15 * 16);
                LaccS = __builtin_amdgcn_mfma_f32_16x16x32_bf16(ones, pf, LaccS, 0, 0, 0);
#pragma unroll
                for (int ds = 0; ds < 4; ++ds)
                    OaccS[ds] = __builtin_amdgcn_mfma_f32_16x16x32_bf16(
                        vf[ks][ds], pf, OaccS[ds], 0, 0, 0);
            }
        }
    };

    // k-loop, unrolled x2 with compile-time buffer bases
#pragma unroll 1
    for (int kt = 0; kt < KT; kt += 2) {
        if (kt + 1 < KT) prefetch(kt + 1, KV1);
        compute(kt, KV0, KV0 + 8192);
        __syncthreads();
        if (kt + 1 >= KT) break;
        if (kt + 2 < KT) prefetch(kt + 2, KV0);
        compute(kt + 1, KV1, KV1 + 8192);
        __syncthreads();
    }

    // epilogue: O^T/l -> per-wave LDS [q][d] -> coalesced 16B stores (both tiles)
#pragma unroll
    for (int which = 0; which < 2; ++which) {
        const floatx4* Oacc = which ? OaccB : OaccS;
        const float invl = 1.f / (which ? LaccB[0] : LaccS[0]);
        const int q0 = which ? q0B : q0S;
#pragma unroll
        for (int ds = 0; ds < 4; ++ds) {
            const int d = ds * 16 + quad * 4;
            uint2 ow;
            ow.x = pack2(Oacc[ds][0] * invl, Oacc[ds][1] * invl);
            ow.y = pack2(Oacc[ds][2] * invl, Oacc[ds][3] * invl);
            *reinterpret_cast<uint2*>(
                Ps + (d >> 3) * 256 + l15 * 16 + (d & 7) * 2) = ow;
        }
#pragma unroll
        for (int it = 0; it < 2; ++it) {
            const int idx = it * 64 + lane;
            const int ch = idx >> 4, q = idx & 15;
            short8 ov = *reinterpret_cast<const short8*>(Ps + ch * 256 + q * 16);
            *reinterpret_cast<short8*>(
                ob + (kvrow + q0 + w * 16 + q) * D_EMBED + h * 64 + ch * 8) = ov;
        }
    }
}

// ---------------------------------------------------------------------------
extern "C" void kernel_launch(void* const* d_in, const int* in_sizes, int n_in,
                              void* d_out, int out_size, void* d_ws, size_t ws_size,
                              hipStream_t stream)
{
    const float* x     = (const float*)d_in[0];   // [4096, 1024]
    const float* w_qkv = (const float*)d_in[1];   // [1024, 3072]
    const float* b_qkv = (const float*)d_in[2];   // [3072]
    const float* w_o   = (const float*)d_in[3];   // [1024, 1024]
    const float* b_o   = (const float*)d_in[4];   // [1024]
    float* out = (float*)d_out;                   // [4096, 1024] fp32

    bf16* xb     = (bf16*)d_ws;                    // [4096][1024]
    bf16* wqkvT  = xb + (size_t)4096 * 1024;       // [3072][1024]
    bf16* woT    = wqkvT + (size_t)3072 * 1024;    // [1024][1024]
    bf16* qbuf   = woT + (size_t)1024 * 1024;      // [4096][1024] (pre-scaled)
    bf16* kbuf   = qbuf + (size_t)4096 * 1024;     // [4096][1024]
    bf16* vtb    = kbuf + (size_t)4096 * 1024;     // [32 bh][64 d][2048 s]
    bf16* attnb  = vtb + (size_t)4096 * 1024;      // [4096][1024]

    dim3 blk(256);

    // fused casts
    prep<<<dim3(5120), blk, 0, stream>>>(x, w_qkv, w_o, xb, wqkvT, woT);

    // QKV projection (q scaled, k row-major, V transposed directly), dbuf
    gemm_qkv<<<dim3(24, 32), blk, 0, stream>>>(xb, wqkvT, b_qkv, qbuf, kbuf, vtb);

    // flash attention: merged-pair causal blocks, K/V dbuf, unrolled x2
    attn_mfma<<<dim3(16, 32), blk, 0, stream>>>(qbuf, kbuf, vtb, attnb);

    // output projection (fp32 out + bias), 512 blocks, dbuf
    gemm_out<<<dim3(16, 32), blk, 0, stream>>>(attnb, woT, b_o, out);
}

// Round 11
// 174.739 us; speedup vs baseline: 1.0341x; 1.0236x over previous
//
#include <hip/hip_runtime.h>
#include <hip/hip_bf16.h>

typedef __hip_bfloat16 bf16;
typedef unsigned short u16;
typedef __attribute__((ext_vector_type(8))) short short8;
typedef __attribute__((ext_vector_type(4))) float floatx4;

#define D_EMBED 1024
#define N_HEADS 16
#define HEAD_DIM 64
#define BATCH 2
#define SEQ 2048
#define ROWS (BATCH * SEQ)          // 4096
#define QKV_COLS (3 * D_EMBED)      // 3072
// exp2-domain scale folded into Q: log2(e)/sqrt(64)
#define QSCALE 0.1803368801f

__device__ __forceinline__ void g2l16(const void* g, void* l) {
    __builtin_amdgcn_global_load_lds(
        (const __attribute__((address_space(1))) unsigned int*)g,
        (__attribute__((address_space(3))) unsigned int*)l,
        16, 0, 0);
}

__device__ __forceinline__ u16 f2b_bits(float f) {
    bf16 h = __float2bfloat16(f);
    u16 u;
    __builtin_memcpy(&u, &h, 2);
    return u;
}

__device__ __forceinline__ unsigned pack2(float a, float b) {   // RNE pack
    return (unsigned)f2b_bits(a) | ((unsigned)f2b_bits(b) << 16);
}

__device__ __forceinline__ float fexp2(float x) {
#if __has_builtin(__builtin_amdgcn_exp2f)
    return __builtin_amdgcn_exp2f(x);
#else
    return exp2f(x);
#endif
}

// pack two fp32 -> two truncated bf16 in one op (low = a, high = b)
__device__ __forceinline__ unsigned permpack(float a, float b) {
#if __has_builtin(__builtin_amdgcn_perm)
    return __builtin_amdgcn_perm(__float_as_uint(b), __float_as_uint(a), 0x07060302u);
#else
    return (__float_as_uint(a) >> 16) | (__float_as_uint(b) & 0xFFFF0000u);
#endif
}

// ---------------------------------------------------------------------------
// Fused prep: cast x -> bf16; transpose+cast w_qkv, w_o.
// ---------------------------------------------------------------------------
__global__ __launch_bounds__(256)
void prep(const float* __restrict__ x, const float* __restrict__ w_qkv,
          const float* __restrict__ w_o, bf16* __restrict__ xb,
          bf16* __restrict__ wqkvT, bf16* __restrict__ woT)
{
    __shared__ u16 T[64][72];
    const int tid = threadIdx.x;
    const int bid = blockIdx.x;

    if (bid < 4096) {
        const int i = bid * 256 + tid;
        const float4 v = reinterpret_cast<const float4*>(x)[i];
        ushort4 o;
        o.x = f2b_bits(v.x); o.y = f2b_bits(v.y);
        o.z = f2b_bits(v.z); o.w = f2b_bits(v.w);
        reinterpret_cast<ushort4*>(xb)[i] = o;
        return;
    }
    const float* in; u16* out; int R, C, bx, by;
    if (bid < 4864) {
        const int t = bid - 4096;
        in = w_qkv; out = reinterpret_cast<u16*>(wqkvT); R = 1024; C = 3072;
        bx = t % 48; by = t / 48;
    } else {
        const int t = bid - 4864;
        in = w_o; out = reinterpret_cast<u16*>(woT); R = 1024; C = 1024;
        bx = t % 16; by = t / 16;
    }
    const int r0 = by * 64, c0 = bx * 64;
#pragma unroll
    for (int it = 0; it < 4; ++it) {
        const int r = (tid >> 4) + it * 16;
        const int c4 = (tid & 15) * 4;
        const float4 v = *reinterpret_cast<const float4*>(in + (size_t)(r0 + r) * C + c0 + c4);
        T[c4 + 0][r] = f2b_bits(v.x);
        T[c4 + 1][r] = f2b_bits(v.y);
        T[c4 + 2][r] = f2b_bits(v.z);
        T[c4 + 3][r] = f2b_bits(v.w);
    }
    __syncthreads();
#pragma unroll
    for (int it = 0; it < 4; ++it) {
        const int rr = (tid >> 4) + it * 16;
        const int cc4 = (tid & 15) * 4;
        ushort4 o = *reinterpret_cast<const ushort4*>(&T[rr][cc4]);
        *reinterpret_cast<ushort4*>(out + (size_t)(c0 + rr) * R + r0 + cc4) = o;
    }
}

// ---------------------------------------------------------------------------
// QKV MFMA GEMM: C[4096,3072] = A @ Bt^T + bias. 128x128 tile, BK=32,
// double-buffered staging. Epilogue: q (scaled) / k row-major bf16; V stored
// TRANSPOSED into vtb[bh*64+d][s] via per-wave LDS column reads.
// ---------------------------------------------------------------------------
__global__ __launch_bounds__(256)
void gemm_qkv(const bf16* __restrict__ A, const bf16* __restrict__ Bt,
              const float* __restrict__ bias,
              bf16* __restrict__ qb, bf16* __restrict__ kb, bf16* __restrict__ vtb)
{
    __shared__ __align__(16) char smem[32768];
    char* BUF0 = smem;            // As 8K + Bs 8K
    char* BUF1 = smem + 16384;

    const int tid = threadIdx.x;
    const int lane = tid & 63, w = tid >> 6;
    const int quad = lane >> 4, l15 = lane & 15;
    const int mw = (w >> 1) * 64, nw = (w & 1) * 64;
    const int blockM = blockIdx.y * 128, blockN = blockIdx.x * 128;

    const int row0 = tid >> 2, ch = tid & 3;
    const int off0 = (tid & ~63) * 16;
    const bf16* Asrc0 = A + (size_t)(blockM + row0) * 1024 + ch * 8;
    const bf16* Asrc1 = Asrc0 + (size_t)64 * 1024;
    const bf16* Bsrc0 = Bt + (size_t)(blockN + row0) * 1024 + ch * 8;
    const bf16* Bsrc1 = Bsrc0 + (size_t)64 * 1024;

    auto stage = [&](int k0, char* buf) {
        g2l16(Asrc0 + k0, buf + off0);
        g2l16(Asrc1 + k0, buf + off0 + 4096);
        g2l16(Bsrc0 + k0, buf + 8192 + off0);
        g2l16(Bsrc1 + k0, buf + 8192 + off0 + 4096);
    };

    floatx4 acc[4][4];
#pragma unroll
    for (int i = 0; i < 4; ++i)
#pragma unroll
        for (int j = 0; j < 4; ++j) acc[i][j] = (floatx4){0.f, 0.f, 0.f, 0.f};

    auto compute = [&](char* buf) {
        short8 af[4], bfr[4];
#pragma unroll
        for (int mi = 0; mi < 4; ++mi)
            af[mi] = *reinterpret_cast<const short8*>(
                buf + (mw + mi * 16 + l15) * 64 + quad * 16);
#pragma unroll
        for (int ni = 0; ni < 4; ++ni)
            bfr[ni] = *reinterpret_cast<const short8*>(
                buf + 8192 + (nw + ni * 16 + l15) * 64 + quad * 16);
#pragma unroll
        for (int mi = 0; mi < 4; ++mi)
#pragma unroll
            for (int ni = 0; ni < 4; ++ni)
                acc[mi][ni] = __builtin_amdgcn_mfma_f32_16x16x32_bf16(
                    af[mi], bfr[ni], acc[mi][ni], 0, 0, 0);
    };

    stage(0, BUF0);
    __syncthreads();
#pragma unroll 1
    for (int k0 = 0; k0 < 1024; k0 += 64) {
        if (k0 + 32 < 1024) stage(k0 + 32, BUF1);
        compute(BUF0);
        __syncthreads();
        if (k0 + 64 < 1024) stage(k0 + 64, BUF0);
        compute(BUF1);
        __syncthreads();
    }

    // epilogue: per-wave LDS repack
    u16* W = reinterpret_cast<u16*>(smem + w * 2304);   // [16 m][stride 72 u16]
    const bool isq = (blockN < 1024);
    const bool isv = (blockN >= 2048);

    float bvn[4];
#pragma unroll
    for (int ni = 0; ni < 4; ++ni) bvn[ni] = bias[blockN + nw + ni * 16 + l15];

    if (!isv) {
        bf16* dstbuf = isq ? qb : kb;
        const int coloff = blockN - (isq ? 0 : 1024);
#pragma unroll
        for (int mi = 0; mi < 4; ++mi) {
#pragma unroll
            for (int ni = 0; ni < 4; ++ni) {
#pragma unroll
                for (int r = 0; r < 4; ++r) {
                    float val = acc[mi][ni][r] + bvn[ni];
                    if (isq) val *= QSCALE;
                    W[(quad * 4 + r) * 72 + ni * 16 + l15] = f2b_bits(val);
                }
            }
#pragma unroll
            for (int half = 0; half < 2; ++half) {
                const int idx = half * 64 + lane;
                const int rowL = idx >> 3, chh = idx & 7;
                short8 v = *reinterpret_cast<const short8*>(W + rowL * 72 + chh * 8);
                const int grow = blockM + mw + mi * 16 + rowL;
                const int gcol = coloff + nw + chh * 8;
                *reinterpret_cast<short8*>(
                    reinterpret_cast<u16*>(dstbuf) + (size_t)grow * 1024 + gcol) = v;
            }
        }
    } else {
        const int col0 = blockN - 2048 + nw;          // multiple of 64
        const int h = col0 >> 6;
        const int bh = (blockM >> 11) * 16 + h;
        const int sb = (blockM & 2047) + mw;
        u16* vdst = reinterpret_cast<u16*>(vtb) + (size_t)bh * 64 * SEQ;
#pragma unroll
        for (int mi = 0; mi < 4; ++mi) {
#pragma unroll
            for (int ni = 0; ni < 4; ++ni) {
#pragma unroll
                for (int r = 0; r < 4; ++r)
                    W[(quad * 4 + r) * 72 + ni * 16 + l15] =
                        f2b_bits(acc[mi][ni][r] + bvn[ni]);
            }
#pragma unroll
            for (int mc = 0; mc < 2; ++mc) {
                u16 tmp[8];
#pragma unroll
                for (int e = 0; e < 8; ++e) tmp[e] = W[(mc * 8 + e) * 72 + lane];
                const int s = sb + mi * 16 + mc * 8;
                *reinterpret_cast<short8*>(vdst + (size_t)lane * SEQ + s) =
                    *reinterpret_cast<const short8*>(tmp);
            }
        }
    }
}

// ---------------------------------------------------------------------------
// Out-proj MFMA GEMM: out[4096,1024] = A @ Bt^T + bias (fp32 out).
// 128m x 64n tile -> 512 blocks (2/CU). Double-buffered staging.
// ---------------------------------------------------------------------------
__global__ __launch_bounds__(256)
void gemm_out(const bf16* __restrict__ A, const bf16* __restrict__ Bt,
              const float* __restrict__ bias, float* __restrict__ outf)
{
    __shared__ __align__(16) char smem[24576];
    char* BUF0 = smem;            // As 8K + Bs 4K
    char* BUF1 = smem + 12288;

    const int tid = threadIdx.x;
    const int lane = tid & 63, w = tid >> 6;
    const int quad = lane >> 4, l15 = lane & 15;
    const int mw = (w >> 1) * 64, nw = (w & 1) * 32;
    const int blockM = blockIdx.y * 128, blockN = blockIdx.x * 64;

    const int row0 = tid >> 2, ch = tid & 3;
    const int off0 = (tid & ~63) * 16;
    const bf16* Asrc0 = A + (size_t)(blockM + row0) * 1024 + ch * 8;
    const bf16* Asrc1 = Asrc0 + (size_t)64 * 1024;
    const bf16* Bsrc0 = Bt + (size_t)(blockN + row0) * 1024 + ch * 8;

    auto stage = [&](int k0, char* buf) {
        g2l16(Asrc0 + k0, buf + off0);
        g2l16(Asrc1 + k0, buf + off0 + 4096);
        g2l16(Bsrc0 + k0, buf + 8192 + off0);
    };

    floatx4 acc[4][2];
#pragma unroll
    for (int i = 0; i < 4; ++i)
#pragma unroll
        for (int j = 0; j < 2; ++j) acc[i][j] = (floatx4){0.f, 0.f, 0.f, 0.f};

    auto compute = [&](char* buf) {
        short8 af[4], bfr[2];
#pragma unroll
        for (int mi = 0; mi < 4; ++mi)
            af[mi] = *reinterpret_cast<const short8*>(
                buf + (mw + mi * 16 + l15) * 64 + quad * 16);
#pragma unroll
        for (int ni = 0; ni < 2; ++ni)
            bfr[ni] = *reinterpret_cast<const short8*>(
                buf + 8192 + (nw + ni * 16 + l15) * 64 + quad * 16);
#pragma unroll
        for (int mi = 0; mi < 4; ++mi)
#pragma unroll
            for (int ni = 0; ni < 2; ++ni)
                acc[mi][ni] = __builtin_amdgcn_mfma_f32_16x16x32_bf16(
                    af[mi], bfr[ni], acc[mi][ni], 0, 0, 0);
    };

    stage(0, BUF0);
    __syncthreads();
#pragma unroll 1
    for (int k0 = 0; k0 < 1024; k0 += 64) {
        if (k0 + 32 < 1024) stage(k0 + 32, BUF1);
        compute(BUF0);
        __syncthreads();
        if (k0 + 64 < 1024) stage(k0 + 64, BUF0);
        compute(BUF1);
        __syncthreads();
    }

    float bvn[2];
#pragma unroll
    for (int ni = 0; ni < 2; ++ni) bvn[ni] = bias[blockN + nw + ni * 16 + l15];

#pragma unroll
    for (int mi = 0; mi < 4; ++mi)
#pragma unroll
        for (int r = 0; r < 4; ++r) {
            const int row = blockM + mw + mi * 16 + quad * 4 + r;
#pragma unroll
            for (int ni = 0; ni < 2; ++ni) {
                const int col = blockN + nw + ni * 16 + l15;
                outf[(size_t)row * 1024 + col] = acc[mi][ni][r] + bvn[ni];
            }
        }
}

// ---------------------------------------------------------------------------
// MFMA flash attention (causal), max-free exp2-domain softmax.
// Merged union k-loop; K/V dbuf unrolled x2. Round 11:
//  - SEPARATE Ps regions per q-tile (PsB/PsS) and interleaved dual compute:
//    two independent S->exp->P->O chains for the scheduler to overlap.
//  - Complementary block swizzle: linear blocks l and l+256 (same CU under
//    round-robin dispatch) get pairs with KT_a + KT_b = 49 (constant).
// LDS: KV dbuf 32K + PsB 8K + PsS 8K = 48 KB.
// ---------------------------------------------------------------------------
__global__ __launch_bounds__(256)
void attn_mfma(const bf16* __restrict__ qb, const bf16* __restrict__ kb,
               const bf16* __restrict__ vtb, bf16* __restrict__ ob)
{
    __shared__ __align__(16) char smem[49152];
    char* KV0 = smem;                     // K 8K + V 8K
    char* KV1 = smem + 16384;             // K 8K + V 8K (initially Q staging)
    const int tid = threadIdx.x;
    const int lane = tid & 63, w = tid >> 6;
    const int quad = lane >> 4, l15 = lane & 15;
    char* PsB = smem + 32768 + w * 2048;  // per-wave [8 kchunk][16 q][16B]
    char* PsS = smem + 40960 + w * 2048;

    // complementary swizzle: l and l+256 share a CU (round-robin heuristic)
    // slot<8: pi=slot ; slot>=8: pi=23-slot  => KT(l) + KT(l+256) = 49
    const int l = blockIdx.x;
    const int bh = l & 31;
    const int slot = l >> 5;
    const int pi = (slot < 8) ? slot : 23 - slot;
    const int b = bh >> 4, h = bh & 15;

    const int qtS = pi, qtB = 31 - pi;
    const int q0S = qtS * 64, q0B = qtB * 64;
    const int KT = qtB + 1;               // 17..32
    const int qrowS = q0S + w * 16 + l15;
    const int qrowB = q0B + w * 16 + l15;

    const size_t kvrow = (size_t)b * SEQ;
    const size_t vbase = (size_t)bh * 64 * SEQ;

    const short8 ones = {0x3F80, 0x3F80, 0x3F80, 0x3F80,
                         0x3F80, 0x3F80, 0x3F80, 0x3F80};   // bf16 1.0 x8

    // hoisted staging geometry: row1 = row0+32, lch identical (32 % 8 == 0)
    const int row0 = tid >> 3;
    const int lch = (tid & 7) ^ (row0 & 7);
    const int loff0 = (tid & ~63) * 16;
    const int loff1 = loff0 + 4096;
    const bf16* ksrc0 = kb + (kvrow + row0) * D_EMBED + h * 64 + lch * 8;
    const bf16* ksrc1 = ksrc0 + (size_t)32 * D_EMBED;
    const bf16* vsrc0 = vtb + vbase + (size_t)row0 * SEQ + lch * 8;
    const bf16* vsrc1 = vsrc0 + (size_t)32 * SEQ;

    // stage Q tiles into KV1 (dead after fragment load) + K/V kt=0 into KV0
    {
        const bf16* qsrcS = qb + (kvrow + q0S + row0) * D_EMBED + h * 64 + lch * 8;
        const bf16* qsrcB = qb + (kvrow + q0B + row0) * D_EMBED + h * 64 + lch * 8;
        g2l16(qsrcS, KV1 + loff0);
        g2l16(qsrcS + (size_t)32 * D_EMBED, KV1 + loff1);
        g2l16(qsrcB, KV1 + 8192 + loff0);
        g2l16(qsrcB + (size_t)32 * D_EMBED, KV1 + 8192 + loff1);
        g2l16(ksrc0, KV0 + loff0);
        g2l16(ksrc1, KV0 + loff1);
        g2l16(vsrc0, KV0 + 8192 + loff0);
        g2l16(vsrc1, KV0 + 8192 + loff1);
    }
    __syncthreads();

    const int qoff = (w * 16 + l15) * 128;
    const int x0 = (quad ^ (l15 & 7)) * 16;
    const int x1 = ((quad + 4) ^ (l15 & 7)) * 16;
    const short8 qS0 = *reinterpret_cast<const short8*>(KV1 + qoff + x0);
    const short8 qS1 = *reinterpret_cast<const short8*>(KV1 + qoff + x1);
    const short8 qB0 = *reinterpret_cast<const short8*>(KV1 + 8192 + qoff + x0);
    const short8 qB1 = *reinterpret_cast<const short8*>(KV1 + 8192 + qoff + x1);
    __syncthreads();    // Q reads done; KV1 free for prefetch

    floatx4 OaccS[4], OaccB[4], LaccS, LaccB;
#pragma unroll
    for (int i = 0; i < 4; ++i) {
        OaccS[i] = (floatx4){0.f, 0.f, 0.f, 0.f};
        OaccB[i] = (floatx4){0.f, 0.f, 0.f, 0.f};
    }
    LaccS = (floatx4){0.f, 0.f, 0.f, 0.f};
    LaccB = (floatx4){0.f, 0.f, 0.f, 0.f};

    auto prefetch = [&](int nkt, char* dst) {
        const size_t ko = (size_t)nkt * 64;
        g2l16(ksrc0 + ko * D_EMBED, dst + loff0);
        g2l16(ksrc1 + ko * D_EMBED, dst + loff1);
        g2l16(vsrc0 + ko, dst + 8192 + loff0);
        g2l16(vsrc1 + ko, dst + 8192 + loff1);
    };

    // interleaved dual-q compute: both chains issued together
    auto compute = [&](int kt, char* Ks, char* Vs) {
        const int k0 = kt * 64;
        const bool doS = (kt <= qtS);
        short8 kf[2][4], vf[2][4];
#pragma unroll
        for (int ms = 0; ms < 4; ++ms) {
            const int roff = (ms * 16 + l15) * 128;
            kf[0][ms] = *reinterpret_cast<const short8*>(Ks + roff + x0);
            kf[1][ms] = *reinterpret_cast<const short8*>(Ks + roff + x1);
        }
#pragma unroll
        for (int ks = 0; ks < 2; ++ks)
#pragma unroll
            for (int ds = 0; ds < 4; ++ds)
                vf[ks][ds] = *reinterpret_cast<const short8*>(
                    Vs + (ds * 16 + l15) * 128 + (((quad + ks * 4) ^ (l15 & 7)) * 16));

        // S MFMAs for both tiles (independent)
        floatx4 SB[4], SS[4];
#pragma unroll
        for (int ms = 0; ms < 4; ++ms) {
            floatx4 t = (floatx4){0.f, 0.f, 0.f, 0.f};
            t = __builtin_amdgcn_mfma_f32_16x16x32_bf16(kf[0][ms], qB0, t, 0, 0, 0);
            SB[ms] = __builtin_amdgcn_mfma_f32_16x16x32_bf16(kf[1][ms], qB1, t, 0, 0, 0);
        }
        if (doS) {
#pragma unroll
            for (int ms = 0; ms < 4; ++ms) {
                floatx4 t = (floatx4){0.f, 0.f, 0.f, 0.f};
                t = __builtin_amdgcn_mfma_f32_16x16x32_bf16(kf[0][ms], qS0, t, 0, 0, 0);
                SS[ms] = __builtin_amdgcn_mfma_f32_16x16x32_bf16(kf[1][ms], qS1, t, 0, 0, 0);
            }
        }

        // exp + Ps writes: big -> PsB, small -> PsS (disjoint regions)
        const bool diagB = (kt == KT - 1);
#pragma unroll
        for (int ms = 0; ms < 4; ++ms) {
            float p[4];
#pragma unroll
            for (int r = 0; r < 4; ++r) {
                float s = SB[ms][r];
                if (diagB && (k0 + ms * 16 + quad * 4 + r) > qrowB) s = -1e30f;
                p[r] = fexp2(s);
            }
            const int k = ms * 16 + quad * 4;
            uint2 pw;
            pw.x = permpack(p[0], p[1]);
            pw.y = permpack(p[2], p[3]);
            *reinterpret_cast<uint2*>(PsB + (k >> 3) * 256 + l15 * 16 + (k & 7) * 2) = pw;
        }
        if (doS) {
            const bool diagS = (kt == qtS);
#pragma unroll
            for (int ms = 0; ms < 4; ++ms) {
                float p[4];
#pragma unroll
                for (int r = 0; r < 4; ++r) {
                    float s = SS[ms][r];
                    if (diagS && (k0 + ms * 16 + quad * 4 + r) > qrowS) s = -1e30f;
                    p[r] = fexp2(s);
                }
                const int k = ms * 16 + quad * 4;
                uint2 pw;
                pw.x = permpack(p[0], p[1]);
                pw.y = permpack(p[2], p[3]);
                *reinterpret_cast<uint2*>(PsS + (k >> 3) * 256 + l15 * 16 + (k & 7) * 2) = pw;
            }
        }

        // O MFMAs, both chains interleaved
#pragma unroll
        for (int ks = 0; ks < 2; ++ks) {
            const short8 pfB = *reinterpret_cast<const short8*>(
                PsB + (ks * 4 + quad) * 256 + l15 * 16);
            LaccB = __builtin_amdgcn_mfma_f32_16x16x32_bf16(ones, pfB, LaccB, 0, 0, 0);
#pragma unroll
            for (int ds = 0; ds < 4; ++ds)
                OaccB[ds] = __builtin_amdgcn_mfma_f32_16x16x32_bf16(
                    vf[ks][ds], pfB, OaccB[ds], 0, 0, 0);
            if (doS) {
                const short8 pfS = *reinterpret_cast<const short8*>(
                    PsS + (ks * 4 + quad) * 256 + l15 * 16);
                LaccS = __builtin_amdgcn_mfma_f32_16x16x32_bf16(ones, pfS, LaccS, 0, 0, 0);
#pragma unroll
                for (int ds = 0; ds < 4; ++ds)
                    OaccS[ds] = __builtin_amdgcn_mfma_f32_16x16x32_bf16(
                        vf[ks][ds], pfS, OaccS[ds], 0, 0, 0);
            }
        }
    };

    // k-loop, unrolled x2 with compile-time buffer bases
#pragma unroll 1
    for (int kt = 0; kt < KT; kt += 2) {
        if (kt + 1 < KT) prefetch(kt + 1, KV1);
        compute(kt, KV0, KV0 + 8192);
        __syncthreads();
        if (kt + 1 >= KT) break;
        if (kt + 2 < KT) prefetch(kt + 2, KV0);
        compute(kt + 1, KV1, KV1 + 8192);
        __syncthreads();
    }

    // epilogue: O^T/l -> per-wave LDS [q][d] -> coalesced 16B stores
#pragma unroll
    for (int which = 0; which < 2; ++which) {
        const floatx4* Oacc = which ? OaccB : OaccS;
        const float invl = 1.f / (which ? LaccB[0] : LaccS[0]);
        const int q0 = which ? q0B : q0S;
#pragma unroll
        for (int ds = 0; ds < 4; ++ds) {
            const int d = ds * 16 + quad * 4;
            uint2 ow;
            ow.x = pack2(Oacc[ds][0] * invl, Oacc[ds][1] * invl);
            ow.y = pack2(Oacc[ds][2] * invl, Oacc[ds][3] * invl);
            *reinterpret_cast<uint2*>(
                PsB + (d >> 3) * 256 + l15 * 16 + (d & 7) * 2) = ow;
        }
#pragma unroll
        for (int it = 0; it < 2; ++it) {
            const int idx = it * 64 + lane;
            const int chh = idx >> 4, q = idx & 15;
            short8 ov = *reinterpret_cast<const short8*>(PsB + chh * 256 + q * 16);
            *reinterpret_cast<short8*>(
                ob + (kvrow + q0 + w * 16 + q) * D_EMBED + h * 64 + chh * 8) = ov;
        }
    }
}

// ---------------------------------------------------------------------------
extern "C" void kernel_launch(void* const* d_in, const int* in_sizes, int n_in,
                              void* d_out, int out_size, void* d_ws, size_t ws_size,
                              hipStream_t stream)
{
    const float* x     = (const float*)d_in[0];   // [4096, 1024]
    const float* w_qkv = (const float*)d_in[1];   // [1024, 3072]
    const float* b_qkv = (const float*)d_in[2];   // [3072]
    const float* w_o   = (const float*)d_in[3];   // [1024, 1024]
    const float* b_o   = (const float*)d_in[4];   // [1024]
    float* out = (float*)d_out;                   // [4096, 1024] fp32

    bf16* xb     = (bf16*)d_ws;                    // [4096][1024]
    bf16* wqkvT  = xb + (size_t)4096 * 1024;       // [3072][1024]
    bf16* woT    = wqkvT + (size_t)3072 * 1024;    // [1024][1024]
    bf16* qbuf   = woT + (size_t)1024 * 1024;      // [4096][1024] (pre-scaled)
    bf16* kbuf   = qbuf + (size_t)4096 * 1024;     // [4096][1024]
    bf16* vtb    = kbuf + (size_t)4096 * 1024;     // [32 bh][64 d][2048 s]
    bf16* attnb  = vtb + (size_t)4096 * 1024;      // [4096][1024]

    dim3 blk(256);

    // fused casts
    prep<<<dim3(5120), blk, 0, stream>>>(x, w_qkv, w_o, xb, wqkvT, woT);

    // QKV projection (q scaled, k row-major, V transposed directly), dbuf
    gemm_qkv<<<dim3(24, 32), blk, 0, stream>>>(xb, wqkvT, b_qkv, qbuf, kbuf, vtb);

    // flash attention: merged-pair causal blocks, dual-Ps interleave,
    // complementary swizzle (1-D grid)
    attn_mfma<<<dim3(512), blk, 0, stream>>>(qbuf, kbuf, vtb, attnb);

    // output projection (fp32 out + bias), 512 blocks, dbuf
    gemm_out<<<dim3(16, 32), blk, 0, stream>>>(attnb, woT, b_o, out);
}